// Round 4
// baseline (484.984 us; speedup 1.0000x reference)
//
#include <hip/hip_runtime.h>

// GIN fused: msg = node_feat[src] + edge_feat; agg = segment_sum(msg, dst);
// out = relu(agg@w1+b1)@w2+b2
// N=50000 nodes, E=800000 edges, H=128.
//
// Round 4: MLP uses float4 LDS reads (was 1 ds_read_b32 per FMA -> LDS-bound)
// and NPB=32; gather processes 2 edges/wave-iteration with float4 lanes
// (2x MLP, half the loop trips), combining halves via __shfl_xor(.,32).

constexpr int NN = 50000;
constexpr int NE = 800000;
constexpr int H  = 128;   // hidden
constexpr int H2 = 256;   // 2*hidden
constexpr int NPB = 32;   // nodes per block in MLP kernel (50000 % 32 != 0 -> guards)

// ---------------------------------------------------------------------------
__global__ __launch_bounds__(256) void zero_kernel(int4* __restrict__ p, int n4)
{
    int i = blockIdx.x * blockDim.x + threadIdx.x;
    if (i < n4) p[i] = make_int4(0, 0, 0, 0);
}

// ---------------------------------------------------------------------------
// CSR build step 1: histogram of edge_dst
// ---------------------------------------------------------------------------
__global__ __launch_bounds__(256) void count_kernel(
    const int* __restrict__ edge_dst, int* __restrict__ count)
{
    int e = blockIdx.x * blockDim.x + threadIdx.x;
    if (e < NE) atomicAdd(&count[edge_dst[e]], 1);
}

// ---------------------------------------------------------------------------
// CSR build step 2: exclusive prefix sum over count[NN] -> offsets[NN+1].
// ---------------------------------------------------------------------------
__global__ __launch_bounds__(1024) void scan_kernel(
    const int* __restrict__ count, int* __restrict__ offsets)
{
    __shared__ int sums[1024];
    const int t  = threadIdx.x;
    const int CH = (NN + 1023) / 1024;          // 49
    const int beg = t * CH;
    const int end = (beg + CH < NN) ? beg + CH : NN;
    int s = 0;
    for (int i = beg; i < end; ++i) s += count[i];
    sums[t] = s;
    __syncthreads();
    for (int off = 1; off < 1024; off <<= 1) {
        int v = (t >= off) ? sums[t - off] : 0;
        __syncthreads();
        if (t >= off) sums[t] += v;
        __syncthreads();
    }
    int run = (t == 0) ? 0 : sums[t - 1];       // exclusive prefix
    for (int i = beg; i < end; ++i) { offsets[i] = run; run += count[i]; }
    if (t == 1023) offsets[NN] = run;           // == NE
}

// ---------------------------------------------------------------------------
// CSR build step 3: place (eid, src) pairs grouped by destination
// ---------------------------------------------------------------------------
__global__ __launch_bounds__(256) void place_kernel(
    const int* __restrict__ edge_dst, const int* __restrict__ edge_src,
    const int* __restrict__ offsets,
    int* __restrict__ cursor, int2* __restrict__ sorted_es)
{
    int e = blockIdx.x * blockDim.x + threadIdx.x;
    if (e < NE) {
        int d = edge_dst[e];
        int pos = offsets[d] + atomicAdd(&cursor[d], 1);
        sorted_es[pos] = make_int2(e, edge_src[e]);
    }
}

// ---------------------------------------------------------------------------
// Gather: one 64-lane wave per node. float4 per lane; lanes 0-31 process edge
// i, lanes 32-63 edge i+1 (two edges per iteration). Halves combined with
// __shfl_xor at the end. No atomics.
// ---------------------------------------------------------------------------
__global__ __launch_bounds__(256) void gather_kernel(
    const float* __restrict__ node_feat,
    const float* __restrict__ edge_feat,
    const int2*  __restrict__ sorted_es,
    const int*   __restrict__ offsets,
    float*       __restrict__ agg)
{
    const int node = blockIdx.x * 4 + (threadIdx.x >> 6);
    const int lane = threadIdx.x & 63;
    const int hh   = lane >> 5;                 // 0: edge i, 1: edge i+1
    const int c4   = (lane & 31) << 2;          // float column (x4)
    const int start = offsets[node];
    const int end   = offsets[node + 1];
    float ax = 0.f, ay = 0.f, az = 0.f, aw = 0.f;
    int i = start;
    #pragma unroll 2
    for (; i + 2 <= end; i += 2) {
        const int2 es = sorted_es[i + hh];
        const float4 ef = *(const float4*)(edge_feat + (size_t)es.x * H + c4);
        const float4 nf = *(const float4*)(node_feat + (size_t)es.y * H + c4);
        ax += ef.x + nf.x;
        ay += ef.y + nf.y;
        az += ef.z + nf.z;
        aw += ef.w + nf.w;
    }
    if (i < end && hh == 0) {                   // odd tail: lower half only
        const int2 es = sorted_es[i];
        const float4 ef = *(const float4*)(edge_feat + (size_t)es.x * H + c4);
        const float4 nf = *(const float4*)(node_feat + (size_t)es.y * H + c4);
        ax += ef.x + nf.x;
        ay += ef.y + nf.y;
        az += ef.z + nf.z;
        aw += ef.w + nf.w;
    }
    ax += __shfl_xor(ax, 32);
    ay += __shfl_xor(ay, 32);
    az += __shfl_xor(az, 32);
    aw += __shfl_xor(aw, 32);
    if (hh == 0) {
        float4 v; v.x = ax; v.y = ay; v.z = az; v.w = aw;
        *(float4*)(agg + (size_t)node * H + c4) = v;
    }
}

// ---------------------------------------------------------------------------
// MLP: 32 nodes per 256-thread block, float4 LDS reads (FMA:LDS = 4:1).
// Layer1: thread t -> h column t, 32 node-accumulators.
// Layer2: thread t -> out column (t&127) for 16 of the 32 nodes.
// ---------------------------------------------------------------------------
__global__ __launch_bounds__(256) void mlp_kernel(
    const float* __restrict__ agg,
    const float* __restrict__ w1, const float* __restrict__ b1,
    const float* __restrict__ w2, const float* __restrict__ b2,
    float*       __restrict__ out)
{
    __shared__ float4 s_in[NPB][H / 4];    // 32 x 32 x 16B = 16 KB
    __shared__ float4 s_h [NPB][H2 / 4];   // 32 x 64 x 16B = 32 KB
    const int t = threadIdx.x;
    const long long base = (long long)blockIdx.x * NPB;

    // stage up to 32 agg rows: 1024 float4, 4 per thread (guarded)
    {
        const float4* src = (const float4*)(agg + base * H);
        const int lim = (int)((long long)NN * (H / 4) - base * (H / 4));
        float4* dst = &s_in[0][0];
        #pragma unroll
        for (int r = 0; r < 4; ++r) {
            const int idx = t + r * 256;
            float4 v; v.x = v.y = v.z = v.w = 0.f;
            if (idx < lim) v = src[idx];
            dst[idx] = v;
        }
    }
    __syncthreads();

    // ---- layer 1: h = relu(agg @ w1 + b1), thread t -> column t ----
    float acc[NPB];
    {
        const float b = b1[t];
        #pragma unroll
        for (int n = 0; n < NPB; ++n) acc[n] = b;
    }
    #pragma unroll 2
    for (int k4 = 0; k4 < H / 4; ++k4) {
        const float wa = w1[(4 * k4 + 0) * H2 + t];
        const float wb = w1[(4 * k4 + 1) * H2 + t];
        const float wc = w1[(4 * k4 + 2) * H2 + t];
        const float wd = w1[(4 * k4 + 3) * H2 + t];
        #pragma unroll
        for (int n = 0; n < NPB; ++n) {
            const float4 a = s_in[n][k4];      // 16B broadcast read
            acc[n] = fmaf(a.x, wa, acc[n]);
            acc[n] = fmaf(a.y, wb, acc[n]);
            acc[n] = fmaf(a.z, wc, acc[n]);
            acc[n] = fmaf(a.w, wd, acc[n]);
        }
    }
    #pragma unroll
    for (int n = 0; n < NPB; ++n)
        ((float*)&s_h[n][0])[t] = fmaxf(acc[n], 0.0f);
    __syncthreads();

    // ---- layer 2: out = h @ w2 + b2 ----
    const int j = t & (H - 1);
    const int g = t >> 7;                      // node half (0/1), wave-uniform
    float acc2[NPB / 2];
    {
        const float b = b2[j];
        #pragma unroll
        for (int n = 0; n < NPB / 2; ++n) acc2[n] = b;
    }
    #pragma unroll 2
    for (int k4 = 0; k4 < H2 / 4; ++k4) {
        const float wa = w2[(4 * k4 + 0) * H + j];
        const float wb = w2[(4 * k4 + 1) * H + j];
        const float wc = w2[(4 * k4 + 2) * H + j];
        const float wd = w2[(4 * k4 + 3) * H + j];
        #pragma unroll
        for (int n = 0; n < NPB / 2; ++n) {
            const float4 h = s_h[g * (NPB / 2) + n][k4];
            acc2[n] = fmaf(h.x, wa, acc2[n]);
            acc2[n] = fmaf(h.y, wb, acc2[n]);
            acc2[n] = fmaf(h.z, wc, acc2[n]);
            acc2[n] = fmaf(h.w, wd, acc2[n]);
        }
    }
    #pragma unroll
    for (int n = 0; n < NPB / 2; ++n) {
        const long long node = base + g * (NPB / 2) + n;
        if (node < NN) out[node * H + j] = acc2[n];
    }
}

// ---------------------------------------------------------------------------
// Fallback scatter (atomic path) if workspace is too small for CSR.
// ---------------------------------------------------------------------------
__global__ __launch_bounds__(256) void scatter_kernel(
    const float* __restrict__ node_feat,
    const float* __restrict__ edge_feat,
    const int*   __restrict__ edge_src,
    const int*   __restrict__ edge_dst,
    float*       __restrict__ agg)
{
    long long tid = (long long)blockIdx.x * blockDim.x + threadIdx.x;
    const long long total = (long long)NE * 32;
    if (tid >= total) return;
    int e = (int)(tid >> 5);
    int q = (int)((tid & 31) << 2);
    int s = edge_src[e];
    int d = edge_dst[e];
    const float4 nf = *(const float4*)(node_feat + (long long)s * H + q);
    const float4 ef = *(const float4*)(edge_feat + (long long)e * H + q);
    float* dst = agg + (long long)d * H + q;
    atomicAdd(dst + 0, nf.x + ef.x);
    atomicAdd(dst + 1, nf.y + ef.y);
    atomicAdd(dst + 2, nf.z + ef.z);
    atomicAdd(dst + 3, nf.w + ef.w);
}

__global__ __launch_bounds__(256) void zero_agg_kernel(float4* __restrict__ p, int n4)
{
    int i = blockIdx.x * blockDim.x + threadIdx.x;
    if (i < n4) p[i] = make_float4(0.f, 0.f, 0.f, 0.f);
}

// ---------------------------------------------------------------------------
extern "C" void kernel_launch(void* const* d_in, const int* in_sizes, int n_in,
                              void* d_out, int out_size, void* d_ws, size_t ws_size,
                              hipStream_t stream)
{
    const float* node_feat = (const float*)d_in[0];
    const float* edge_feat = (const float*)d_in[1];
    const int*   edge_src  = (const int*)  d_in[2];
    const int*   edge_dst  = (const int*)  d_in[3];
    const float* w1 = (const float*)d_in[4];
    const float* b1 = (const float*)d_in[5];
    const float* w2 = (const float*)d_in[6];
    const float* b2 = (const float*)d_in[7];
    float* out = (float*)d_out;

    // Workspace layout (256-B aligned regions)
    const size_t count_b   = ((size_t)NN * 4 + 255) & ~(size_t)255;       // 200 KB
    const size_t cursor_b  = count_b;                                      // 200 KB
    const size_t offs_b    = (((size_t)NN + 1) * 4 + 255) & ~(size_t)255;  // 200 KB
    const size_t es_b      = ((size_t)NE * 8 + 255) & ~(size_t)255;        // 6.4 MB
    const size_t agg_b     = (size_t)NN * H * sizeof(float);               // 25.6 MB
    const size_t need      = count_b + cursor_b + offs_b + es_b + agg_b;   // ~32.6 MB

    const int mlp_grid = (NN + NPB - 1) / NPB;   // 1563

    if (ws_size >= need) {
        char* p = (char*)d_ws;
        int*   count     = (int*)p;              p += count_b;
        int*   cursor    = (int*)p;              p += cursor_b;
        int*   offsets   = (int*)p;              p += offs_b;
        int2*  sorted_es = (int2*)p;             p += es_b;
        float* agg       = (float*)p;

        {
            const int n4 = (int)((count_b + cursor_b) / 16);
            zero_kernel<<<(n4 + 255) / 256, 256, 0, stream>>>((int4*)d_ws, n4);
        }

        const int eb = 256, eg = (NE + eb - 1) / eb;   // 3125
        count_kernel<<<eg, eb, 0, stream>>>(edge_dst, count);
        scan_kernel<<<1, 1024, 0, stream>>>(count, offsets);
        place_kernel<<<eg, eb, 0, stream>>>(edge_dst, edge_src, offsets, cursor, sorted_es);
        gather_kernel<<<NN / 4, 256, 0, stream>>>(
            node_feat, edge_feat, sorted_es, offsets, agg);
        mlp_kernel<<<mlp_grid, 256, 0, stream>>>(agg, w1, b1, w2, b2, out);
    } else {
        // Fallback: atomic path
        const size_t agg_bytes = (size_t)NN * H * sizeof(float);
        float* agg = (ws_size >= agg_bytes) ? (float*)d_ws : out;
        {
            const int n4 = (int)(agg_bytes / 16);
            zero_agg_kernel<<<(n4 + 255) / 256, 256, 0, stream>>>((float4*)agg, n4);
        }
        const long long total = (long long)NE * 32;
        const int block = 256;
        const int grid  = (int)((total + block - 1) / block);
        scatter_kernel<<<grid, block, 0, stream>>>(
            node_feat, edge_feat, edge_src, edge_dst, agg);
        mlp_kernel<<<mlp_grid, 256, 0, stream>>>(agg, w1, b1, w2, b2, out);
    }
}